// Round 1
// baseline (908.564 us; speedup 1.0000x reference)
//
#include <hip/hip_runtime.h>
#include <hip/hip_bf16.h>
#include <stdint.h>

// Problem constants (T=128, B=64, H=1024)
#define TT 128
#define BB 64
#define HH 1024
#define MM (TT * BB)   // 8192 rows of the two GEMMs

// ---------------------------------------------------------------------------
// Kernel 1: x_proj[m][n] = sum_k X[m][k] * W1[n][k], fp32 in, fp64 accumulate.
// Must be (near-)exact: LIF hard threshold makes spike decisions sensitive to
// ~1e-6 errors; fp64 matches the fp64 numpy reference with zero spike flips.
// Tile 64x64, BK=16, 256 threads, 4x4 micro-tile per thread.
// ---------------------------------------------------------------------------
__global__ __launch_bounds__(256) void gemm1_f64(const float* __restrict__ X,
                                                 const float* __restrict__ W,
                                                 double* __restrict__ C) {
    __shared__ double Xs[64][17];   // +1 pad to break power-of-2 strides
    __shared__ double Ws[64][17];

    const int tid = threadIdx.x;
    const int m0 = blockIdx.x * 64;   // 128 blocks
    const int n0 = blockIdx.y * 64;   // 16 blocks
    const int tx = tid & 15;          // n direction
    const int ty = tid >> 4;          // m direction

    double acc[4][4] = {};

    const int lr = tid >> 4;   // load row group 0..15
    const int lc = tid & 15;   // load col 0..15

    for (int k0 = 0; k0 < HH; k0 += 16) {
#pragma unroll
        for (int i = 0; i < 4; i++) {
            const int row = lr + i * 16;
            Xs[row][lc] = (double)X[(size_t)(m0 + row) * HH + k0 + lc];
            Ws[row][lc] = (double)W[(size_t)(n0 + row) * HH + k0 + lc];
        }
        __syncthreads();
#pragma unroll
        for (int kk = 0; kk < 16; kk++) {
            double a[4], b[4];
#pragma unroll
            for (int i = 0; i < 4; i++) a[i] = Xs[ty * 4 + i][kk];
#pragma unroll
            for (int j = 0; j < 4; j++) b[j] = Ws[tx * 4 + j][kk];
#pragma unroll
            for (int i = 0; i < 4; i++)
#pragma unroll
                for (int j = 0; j < 4; j++)
                    acc[i][j] = fma(a[i], b[j], acc[i][j]);
        }
        __syncthreads();
    }

#pragma unroll
    for (int i = 0; i < 4; i++)
#pragma unroll
        for (int j = 0; j < 4; j++)
            C[(size_t)(m0 + ty * 4 + i) * HH + n0 + tx * 4 + j] = acc[i][j];
}

// ---------------------------------------------------------------------------
// Kernel 2: LIF scan over T in fp64 (matches fp64 reference scan exactly).
// h = v + (x - v)/2 ; s = (h >= 1) ; v = s ? 0 : h.  Emits bf16 spikes {0,1}.
// One thread per (b,h) lane; reads are coalesced across threads per t.
// ---------------------------------------------------------------------------
__global__ __launch_bounds__(256) void lif_scan(const double* __restrict__ xp,
                                                unsigned short* __restrict__ sp) {
    const int idx = blockIdx.x * 256 + threadIdx.x;   // 0 .. B*H-1
    const size_t stride = (size_t)BB * HH;            // 65536
    double v = 0.0;
#pragma unroll 4
    for (int t = 0; t < TT; t++) {
        const double x = xp[(size_t)t * stride + idx];
        const double h = v + (x - v) * 0.5;
        const bool s = (h >= 1.0);
        v = s ? 0.0 : h;
        sp[(size_t)t * stride + idx] = s ? (unsigned short)0x3F80 : (unsigned short)0;
    }
}

// ---------------------------------------------------------------------------
// Kernel 3: cast W2 fp32 -> bf16 (spikes are exact {0,1}; bf16 W2 rounding
// contributes ~4e-4 output error, far under the 2.3e-2 threshold).
// ---------------------------------------------------------------------------
__global__ __launch_bounds__(256) void cast_bf16(const float* __restrict__ src,
                                                 unsigned short* __restrict__ dst,
                                                 int n) {
    const int i = blockIdx.x * 256 + threadIdx.x;
    if (i < n) {
        __hip_bfloat16 b = __float2bfloat16(src[i]);
        dst[i] = *reinterpret_cast<unsigned short*>(&b);
    }
}

// ---------------------------------------------------------------------------
// Kernel 4: out[m][n] = sum_k S[m][k] * W2[n][k] in bf16 MFMA (fp32 accum).
// 128x128 tile, 256 threads = 4 waves in 2x2, each wave does 4x4 frags of
// mfma_f32_16x16x32_bf16.  Verified layouts (learn_hip m89/m91):
//   A[m][k]: m = lane&15, k = (lane>>4)*8 + j
//   C/D    : col = lane&15, row = (lane>>4)*4 + reg
// ---------------------------------------------------------------------------
typedef __attribute__((ext_vector_type(8))) short bf16x8;
typedef __attribute__((ext_vector_type(4))) float f32x4;

__global__ __launch_bounds__(256) void gemm2_mfma(const unsigned short* __restrict__ S,
                                                  const unsigned short* __restrict__ W,
                                                  float* __restrict__ O) {
    __shared__ short As[128 * 32];   // 8 KB, row-major [row][k], unpadded
    __shared__ short Bs[128 * 32];   // 8 KB

    const int tid = threadIdx.x;
    const int lane = tid & 63;
    const int wave = tid >> 6;
    const int m0 = blockIdx.x * 128;   // 64 blocks
    const int n0 = blockIdx.y * 128;   // 8 blocks
    const int wm = (wave >> 1) * 64;
    const int wn = (wave & 1) * 64;

    const int rsel = lane & 15;
    const int qk = (lane >> 4) * 8;   // k offset within BK=32

    f32x4 acc[4][4] = {};

    for (int k0 = 0; k0 < HH; k0 += 32) {
        // stage A and B tiles: 128 rows x 32 bf16 = 512 chunks of 16 B each
#pragma unroll
        for (int p = 0; p < 2; p++) {
            const int c = tid + p * 256;     // chunk 0..511
            const int row = c >> 2;          // 4 chunks per row
            const int part = c & 3;
            *reinterpret_cast<int4*>(&As[c * 8]) =
                *reinterpret_cast<const int4*>(&S[(size_t)(m0 + row) * HH + k0 + part * 8]);
            *reinterpret_cast<int4*>(&Bs[c * 8]) =
                *reinterpret_cast<const int4*>(&W[(size_t)(n0 + row) * HH + k0 + part * 8]);
        }
        __syncthreads();

        bf16x8 a[4], b[4];
#pragma unroll
        for (int mi = 0; mi < 4; mi++)
            a[mi] = *reinterpret_cast<bf16x8*>(&As[(wm + mi * 16 + rsel) * 32 + qk]);
#pragma unroll
        for (int ni = 0; ni < 4; ni++)
            b[ni] = *reinterpret_cast<bf16x8*>(&Bs[(wn + ni * 16 + rsel) * 32 + qk]);

#pragma unroll
        for (int mi = 0; mi < 4; mi++)
#pragma unroll
            for (int ni = 0; ni < 4; ni++)
                acc[mi][ni] = __builtin_amdgcn_mfma_f32_16x16x32_bf16(
                    a[mi], b[ni], acc[mi][ni], 0, 0, 0);

        __syncthreads();
    }

    const int col = lane & 15;
    const int quad = lane >> 4;
#pragma unroll
    for (int mi = 0; mi < 4; mi++)
#pragma unroll
        for (int ni = 0; ni < 4; ni++) {
            const int m = m0 + wm + mi * 16 + quad * 4;
            const int n = n0 + wn + ni * 16 + col;
            float* dst = &O[(size_t)m * HH + n];
#pragma unroll
            for (int r = 0; r < 4; r++)
                dst[(size_t)r * HH] = acc[mi][ni][r];
        }
}

// ---------------------------------------------------------------------------
// Launch
// ---------------------------------------------------------------------------
extern "C" void kernel_launch(void* const* d_in, const int* in_sizes, int n_in,
                              void* d_out, int out_size, void* d_ws, size_t ws_size,
                              hipStream_t stream) {
    const float* x  = (const float*)d_in[0];   // [T,B,H] fp32
    const float* W1 = (const float*)d_in[1];   // [H,H] fp32
    const float* W2 = (const float*)d_in[2];   // [H,H] fp32
    float* out = (float*)d_out;                // [T,B,H] fp32

    char* ws = (char*)d_ws;
    // ws layout: [0, 64 MiB) x_proj f64 ; [64, 80 MiB) spikes bf16 ; [80, 82 MiB) W2 bf16
    double* xp = (double*)ws;
    unsigned short* sp  = (unsigned short*)(ws + (size_t)MM * HH * sizeof(double));
    unsigned short* w2b = (unsigned short*)(ws + (size_t)MM * HH * sizeof(double)
                                               + (size_t)MM * HH * sizeof(unsigned short));

    // GEMM1 in fp64
    dim3 g1(MM / 64, HH / 64);
    gemm1_f64<<<g1, 256, 0, stream>>>(x, W1, xp);

    // W2 -> bf16 (independent of gemm1; stream order is fine)
    cast_bf16<<<(HH * HH + 255) / 256, 256, 0, stream>>>(W2, w2b, HH * HH);

    // LIF scan in fp64 -> bf16 spikes
    lif_scan<<<(BB * HH) / 256, 256, 0, stream>>>(xp, sp);

    // GEMM2 in bf16 MFMA
    dim3 g2(MM / 128, HH / 128);
    gemm2_mfma<<<g2, 256, 0, stream>>>(sp, w2b, out);
}

// Round 2
// 349.607 us; speedup vs baseline: 2.5988x; 2.5988x over previous
//
#include <hip/hip_runtime.h>
#include <hip/hip_bf16.h>
#include <stdint.h>

// Problem constants (T=128, B=64, H=1024)
#define TT 128
#define BB 64
#define HH 1024
#define MM (TT * BB)          // 8192 rows of the two GEMMs
#define NLANE (BB * HH)       // 65536 scan lanes
#define DELTA 3.0e-4          // flag band around spike threshold (realized max err ~6e-5)

typedef __attribute__((ext_vector_type(8))) short bf16x8;
typedef __attribute__((ext_vector_type(4))) float f32x4;

static __device__ __forceinline__ unsigned short bf16_bits(float f) {
    __hip_bfloat16 b = __float2bfloat16(f);
    return *reinterpret_cast<unsigned short*>(&b);
}

// ---------------------------------------------------------------------------
// Split fp32 -> bf16 hi + bf16 lo (hi = bf16(x), lo = bf16(x - hi)).
// Vectorized float4 per thread.
// ---------------------------------------------------------------------------
__global__ __launch_bounds__(256) void split2_kernel(const float* __restrict__ src,
                                                     unsigned short* __restrict__ hi,
                                                     unsigned short* __restrict__ lo,
                                                     int n4) {
    const int i = blockIdx.x * 256 + threadIdx.x;
    if (i >= n4) return;
    float4 x = reinterpret_cast<const float4*>(src)[i];
    ushort4 h, l;
    {
        float v[4] = {x.x, x.y, x.z, x.w};
        unsigned short hb[4], lb[4];
#pragma unroll
        for (int c = 0; c < 4; c++) {
            hb[c] = bf16_bits(v[c]);
            __hip_bfloat16 hh = *reinterpret_cast<__hip_bfloat16*>(&hb[c]);
            lb[c] = bf16_bits(v[c] - __bfloat162float(hh));
        }
        h = make_ushort4(hb[0], hb[1], hb[2], hb[3]);
        l = make_ushort4(lb[0], lb[1], lb[2], lb[3]);
    }
    reinterpret_cast<ushort4*>(hi)[i] = h;
    reinterpret_cast<ushort4*>(lo)[i] = l;
}

// ---------------------------------------------------------------------------
// Cast W2 fp32 -> bf16 (spikes are exact {0,1}; bf16 W2 rounding gives ~4e-3
// output error vs 2.3e-2 threshold — validated in round 1).
// ---------------------------------------------------------------------------
__global__ __launch_bounds__(256) void cast_bf16(const float* __restrict__ src,
                                                 unsigned short* __restrict__ dst,
                                                 int n) {
    const int i = blockIdx.x * 256 + threadIdx.x;
    if (i < n) dst[i] = bf16_bits(src[i]);
}

// ---------------------------------------------------------------------------
// GEMM1 via 3-pass split-bf16 MFMA: C = XhiWhi + XhiWlo + XloWhi (fp32 accum).
// 128x128 tile, BK=32, 4 waves 2x2, mfma_f32_16x16x32_bf16 (layouts verified
// round 1):  A[m][k]: m=lane&15, k=(lane>>4)*8+j ; C/D: col=lane&15,
// row=(lane>>4)*4+reg.
// ---------------------------------------------------------------------------
__global__ __launch_bounds__(256) void gemm1_mfma(const unsigned short* __restrict__ Ah,
                                                  const unsigned short* __restrict__ Al,
                                                  const unsigned short* __restrict__ Bh,
                                                  const unsigned short* __restrict__ Bl,
                                                  float* __restrict__ C) {
    __shared__ short AsH[128 * 32];
    __shared__ short AsL[128 * 32];
    __shared__ short BsH[128 * 32];
    __shared__ short BsL[128 * 32];

    const int tid = threadIdx.x;
    const int lane = tid & 63;
    const int wave = tid >> 6;
    const int m0 = blockIdx.x * 128;   // 64 blocks
    const int n0 = blockIdx.y * 128;   // 8 blocks
    const int wm = (wave >> 1) * 64;
    const int wn = (wave & 1) * 64;

    const int rsel = lane & 15;
    const int qk = (lane >> 4) * 8;

    f32x4 acc[4][4] = {};

    for (int k0 = 0; k0 < HH; k0 += 32) {
#pragma unroll
        for (int p = 0; p < 2; p++) {
            const int c = tid + p * 256;     // chunk 0..511 (16 B each)
            const int row = c >> 2;
            const int part = c & 3;
            const size_t goA = (size_t)(m0 + row) * HH + k0 + part * 8;
            const size_t goB = (size_t)(n0 + row) * HH + k0 + part * 8;
            *reinterpret_cast<int4*>(&AsH[c * 8]) = *reinterpret_cast<const int4*>(&Ah[goA]);
            *reinterpret_cast<int4*>(&AsL[c * 8]) = *reinterpret_cast<const int4*>(&Al[goA]);
            *reinterpret_cast<int4*>(&BsH[c * 8]) = *reinterpret_cast<const int4*>(&Bh[goB]);
            *reinterpret_cast<int4*>(&BsL[c * 8]) = *reinterpret_cast<const int4*>(&Bl[goB]);
        }
        __syncthreads();

        bf16x8 aH[4], aL[4], bH[4], bL[4];
#pragma unroll
        for (int mi = 0; mi < 4; mi++) {
            const int r = (wm + mi * 16 + rsel) * 32 + qk;
            aH[mi] = *reinterpret_cast<bf16x8*>(&AsH[r]);
            aL[mi] = *reinterpret_cast<bf16x8*>(&AsL[r]);
        }
#pragma unroll
        for (int ni = 0; ni < 4; ni++) {
            const int r = (wn + ni * 16 + rsel) * 32 + qk;
            bH[ni] = *reinterpret_cast<bf16x8*>(&BsH[r]);
            bL[ni] = *reinterpret_cast<bf16x8*>(&BsL[r]);
        }

#pragma unroll
        for (int mi = 0; mi < 4; mi++)
#pragma unroll
            for (int ni = 0; ni < 4; ni++) {
                acc[mi][ni] = __builtin_amdgcn_mfma_f32_16x16x32_bf16(aH[mi], bH[ni], acc[mi][ni], 0, 0, 0);
                acc[mi][ni] = __builtin_amdgcn_mfma_f32_16x16x32_bf16(aH[mi], bL[ni], acc[mi][ni], 0, 0, 0);
                acc[mi][ni] = __builtin_amdgcn_mfma_f32_16x16x32_bf16(aL[mi], bH[ni], acc[mi][ni], 0, 0, 0);
            }

        __syncthreads();
    }

    const int col = lane & 15;
    const int quad = lane >> 4;
#pragma unroll
    for (int mi = 0; mi < 4; mi++)
#pragma unroll
        for (int ni = 0; ni < 4; ni++) {
            const int m = m0 + wm + mi * 16 + quad * 4;
            const int n = n0 + wn + ni * 16 + col;
            float* dst = &C[(size_t)m * HH + n];
#pragma unroll
            for (int r = 0; r < 4; r++)
                dst[(size_t)r * HH] = acc[mi][ni][r];
        }
}

// ---------------------------------------------------------------------------
// LIF scan (f64 arithmetic on fp32 x_proj) + near-threshold lane flagging.
// ---------------------------------------------------------------------------
__global__ __launch_bounds__(256) void lif_scan_flag(const float* __restrict__ xp,
                                                     unsigned short* __restrict__ sp,
                                                     int* __restrict__ count,
                                                     int* __restrict__ list) {
    const int idx = blockIdx.x * 256 + threadIdx.x;   // 0 .. NLANE-1
    double v = 0.0;
    bool flg = false;
#pragma unroll 4
    for (int t = 0; t < TT; t++) {
        const double x = (double)xp[(size_t)t * NLANE + idx];
        const double h = v + (x - v) * 0.5;
        const bool s = (h >= 1.0);
        flg |= (fabs(h - 1.0) < DELTA);
        v = s ? 0.0 : h;
        sp[(size_t)t * NLANE + idx] = s ? (unsigned short)0x3F80 : (unsigned short)0;
    }
    if (flg) {
        const int i = atomicAdd(count, 1);
        list[i] = idx;
    }
}

// ---------------------------------------------------------------------------
// Exact fp64 recompute of flagged lanes: x_proj[t,(b,h)] = X[t,b,:]·W1[h,:]
// in f64 for all t, then exact f64 scan, overwriting the lane's spikes.
// One block per flagged lane (grid-stride over list); wave w handles
// t = w, w+4, ... ; 64 lanes strided-coalesced over K, shuffle-reduced.
// ---------------------------------------------------------------------------
__global__ __launch_bounds__(256) void recompute_lanes(const float* __restrict__ X,
                                                       const float* __restrict__ W1,
                                                       const int* __restrict__ count,
                                                       const int* __restrict__ list,
                                                       unsigned short* __restrict__ sp) {
    __shared__ double hbuf[TT];
    const int cnt = *count;
    const int wv = threadIdx.x >> 6;
    const int ln = threadIdx.x & 63;

    for (int li = blockIdx.x; li < cnt; li += gridDim.x) {
        const int lane = list[li];
        const int b = lane >> 10;       // lane = b*HH + h
        const int h = lane & (HH - 1);
        const float* wrow = W1 + (size_t)h * HH;

        for (int t = wv; t < TT; t += 4) {
            const float* xrow = X + (size_t)(t * BB + b) * HH;
            double s = 0.0;
#pragma unroll 4
            for (int k = ln; k < HH; k += 64)
                s = fma((double)xrow[k], (double)wrow[k], s);
#pragma unroll
            for (int off = 32; off >= 1; off >>= 1)
                s += __shfl_down(s, off);
            if (ln == 0) hbuf[t] = s;
        }
        __syncthreads();

        if (threadIdx.x == 0) {
            double v = 0.0;
            for (int t = 0; t < TT; t++) {
                const double hh = v + (hbuf[t] - v) * 0.5;
                const bool sk = (hh >= 1.0);
                v = sk ? 0.0 : hh;
                sp[(size_t)t * NLANE + lane] = sk ? (unsigned short)0x3F80 : (unsigned short)0;
            }
        }
        __syncthreads();
    }
}

// ---------------------------------------------------------------------------
// GEMM2: out = S · W2^T in bf16 MFMA (validated round 1, unchanged).
// ---------------------------------------------------------------------------
__global__ __launch_bounds__(256) void gemm2_mfma(const unsigned short* __restrict__ S,
                                                  const unsigned short* __restrict__ W,
                                                  float* __restrict__ O) {
    __shared__ short As[128 * 32];
    __shared__ short Bs[128 * 32];

    const int tid = threadIdx.x;
    const int lane = tid & 63;
    const int wave = tid >> 6;
    const int m0 = blockIdx.x * 128;
    const int n0 = blockIdx.y * 128;
    const int wm = (wave >> 1) * 64;
    const int wn = (wave & 1) * 64;

    const int rsel = lane & 15;
    const int qk = (lane >> 4) * 8;

    f32x4 acc[4][4] = {};

    for (int k0 = 0; k0 < HH; k0 += 32) {
#pragma unroll
        for (int p = 0; p < 2; p++) {
            const int c = tid + p * 256;
            const int row = c >> 2;
            const int part = c & 3;
            *reinterpret_cast<int4*>(&As[c * 8]) =
                *reinterpret_cast<const int4*>(&S[(size_t)(m0 + row) * HH + k0 + part * 8]);
            *reinterpret_cast<int4*>(&Bs[c * 8]) =
                *reinterpret_cast<const int4*>(&W[(size_t)(n0 + row) * HH + k0 + part * 8]);
        }
        __syncthreads();

        bf16x8 a[4], b[4];
#pragma unroll
        for (int mi = 0; mi < 4; mi++)
            a[mi] = *reinterpret_cast<bf16x8*>(&As[(wm + mi * 16 + rsel) * 32 + qk]);
#pragma unroll
        for (int ni = 0; ni < 4; ni++)
            b[ni] = *reinterpret_cast<bf16x8*>(&Bs[(wn + ni * 16 + rsel) * 32 + qk]);

#pragma unroll
        for (int mi = 0; mi < 4; mi++)
#pragma unroll
            for (int ni = 0; ni < 4; ni++)
                acc[mi][ni] = __builtin_amdgcn_mfma_f32_16x16x32_bf16(
                    a[mi], b[ni], acc[mi][ni], 0, 0, 0);

        __syncthreads();
    }

    const int col = lane & 15;
    const int quad = lane >> 4;
#pragma unroll
    for (int mi = 0; mi < 4; mi++)
#pragma unroll
        for (int ni = 0; ni < 4; ni++) {
            const int m = m0 + wm + mi * 16 + quad * 4;
            const int n = n0 + wn + ni * 16 + col;
            float* dst = &O[(size_t)m * HH + n];
#pragma unroll
            for (int r = 0; r < 4; r++)
                dst[(size_t)r * HH] = acc[mi][ni][r];
        }
}

// ---------------------------------------------------------------------------
// Launch
// ---------------------------------------------------------------------------
extern "C" void kernel_launch(void* const* d_in, const int* in_sizes, int n_in,
                              void* d_out, int out_size, void* d_ws, size_t ws_size,
                              hipStream_t stream) {
    const float* x  = (const float*)d_in[0];   // [T,B,H] fp32
    const float* W1 = (const float*)d_in[1];   // [H,H] fp32
    const float* W2 = (const float*)d_in[2];   // [H,H] fp32
    float* out = (float*)d_out;                // [T,B,H] fp32

    char* ws = (char*)d_ws;
    const size_t szX = (size_t)MM * HH;        // 8.4M elems
    const size_t szW = (size_t)HH * HH;        // 1M elems

    // ws layout (spikes overlay Xhi after gemm1 consumed it):
    unsigned short* Xhi  = (unsigned short*)ws;                       // 16.78 MB
    unsigned short* Xlo  = Xhi + szX;                                 // 16.78 MB
    unsigned short* W1hi = Xlo + szX;                                 //  2 MB
    unsigned short* W1lo = W1hi + szW;                                //  2 MB
    unsigned short* w2b  = W1lo + szW;                                //  2 MB
    int*            list = (int*)(w2b + szW);                         // 256 KB
    int*            cnt  = list + NLANE;                              // 4 B
    float*          xp   = (float*)(((uintptr_t)(cnt + 64) + 255) & ~(uintptr_t)255); // 33.5 MB
    unsigned short* sp   = Xhi;   // overlay: spikes reuse Xhi region

    hipMemsetAsync(cnt, 0, sizeof(int), stream);

    split2_kernel<<<(int)(szX / 4 / 256), 256, 0, stream>>>(x, Xhi, Xlo, (int)(szX / 4));
    split2_kernel<<<(int)(szW / 4 / 256), 256, 0, stream>>>(W1, W1hi, W1lo, (int)(szW / 4));
    cast_bf16<<<(int)((szW + 255) / 256), 256, 0, stream>>>(W2, w2b, (int)szW);

    dim3 g1(MM / 128, HH / 128);
    gemm1_mfma<<<g1, 256, 0, stream>>>(Xhi, Xlo, W1hi, W1lo, xp);

    lif_scan_flag<<<NLANE / 256, 256, 0, stream>>>(xp, sp, cnt, list);

    recompute_lanes<<<256, 256, 0, stream>>>(x, W1, cnt, list, sp);

    dim3 g2(MM / 128, HH / 128);
    gemm2_mfma<<<g2, 256, 0, stream>>>(sp, w2b, out);
}

// Round 3
// 263.927 us; speedup vs baseline: 3.4425x; 1.3246x over previous
//
#include <hip/hip_runtime.h>
#include <hip/hip_bf16.h>
#include <stdint.h>

// Problem constants (T=128, B=64, H=1024)
#define TT 128
#define BB 64
#define HH 1024
#define MM (TT * BB)          // 8192 rows of the two GEMMs
#define NLANE (BB * HH)       // 65536 scan lanes
#define DELTA 3.0e-4          // flag band around spike threshold (realized max err ~6e-5)
#define CAPL 32768            // hraw capacity in lanes (overlay on xp region)

typedef __attribute__((ext_vector_type(8))) short bf16x8;
typedef __attribute__((ext_vector_type(4))) float f32x4;

static __device__ __forceinline__ unsigned short bf16_bits(float f) {
    __hip_bfloat16 b = __float2bfloat16(f);
    return *reinterpret_cast<unsigned short*>(&b);
}

// ---------------------------------------------------------------------------
// Split fp32 -> bf16 hi + bf16 lo (hi = bf16(x), lo = bf16(x - hi)).
// ---------------------------------------------------------------------------
__global__ __launch_bounds__(256) void split2_kernel(const float* __restrict__ src,
                                                     unsigned short* __restrict__ hi,
                                                     unsigned short* __restrict__ lo,
                                                     int n4) {
    const int i = blockIdx.x * 256 + threadIdx.x;
    if (i >= n4) return;
    float4 x = reinterpret_cast<const float4*>(src)[i];
    float v[4] = {x.x, x.y, x.z, x.w};
    unsigned short hb[4], lb[4];
#pragma unroll
    for (int c = 0; c < 4; c++) {
        hb[c] = bf16_bits(v[c]);
        __hip_bfloat16 hh = *reinterpret_cast<__hip_bfloat16*>(&hb[c]);
        lb[c] = bf16_bits(v[c] - __bfloat162float(hh));
    }
    reinterpret_cast<ushort4*>(hi)[i] = make_ushort4(hb[0], hb[1], hb[2], hb[3]);
    reinterpret_cast<ushort4*>(lo)[i] = make_ushort4(lb[0], lb[1], lb[2], lb[3]);
}

// ---------------------------------------------------------------------------
// Cast W2 fp32 -> bf16 (validated: contributes absmax ~4e-3 << 2.3e-2).
// ---------------------------------------------------------------------------
__global__ __launch_bounds__(256) void cast_bf16(const float* __restrict__ src,
                                                 unsigned short* __restrict__ dst,
                                                 int n) {
    const int i = blockIdx.x * 256 + threadIdx.x;
    if (i < n) dst[i] = bf16_bits(src[i]);
}

// ---------------------------------------------------------------------------
// GEMM1 via 3-pass split-bf16 MFMA: C = XhiWhi + XhiWlo + XloWhi (fp32 accum).
// 128x128 tile, BK=32, 4 waves 2x2.  Layouts verified rounds 1-2.
// ---------------------------------------------------------------------------
__global__ __launch_bounds__(256) void gemm1_mfma(const unsigned short* __restrict__ Ah,
                                                  const unsigned short* __restrict__ Al,
                                                  const unsigned short* __restrict__ Bh,
                                                  const unsigned short* __restrict__ Bl,
                                                  float* __restrict__ C) {
    __shared__ short AsH[128 * 32];
    __shared__ short AsL[128 * 32];
    __shared__ short BsH[128 * 32];
    __shared__ short BsL[128 * 32];

    const int tid = threadIdx.x;
    const int lane = tid & 63;
    const int wave = tid >> 6;
    const int m0 = blockIdx.x * 128;
    const int n0 = blockIdx.y * 128;
    const int wm = (wave >> 1) * 64;
    const int wn = (wave & 1) * 64;

    const int rsel = lane & 15;
    const int qk = (lane >> 4) * 8;

    f32x4 acc[4][4] = {};

    for (int k0 = 0; k0 < HH; k0 += 32) {
#pragma unroll
        for (int p = 0; p < 2; p++) {
            const int c = tid + p * 256;
            const int row = c >> 2;
            const int part = c & 3;
            const size_t goA = (size_t)(m0 + row) * HH + k0 + part * 8;
            const size_t goB = (size_t)(n0 + row) * HH + k0 + part * 8;
            *reinterpret_cast<int4*>(&AsH[c * 8]) = *reinterpret_cast<const int4*>(&Ah[goA]);
            *reinterpret_cast<int4*>(&AsL[c * 8]) = *reinterpret_cast<const int4*>(&Al[goA]);
            *reinterpret_cast<int4*>(&BsH[c * 8]) = *reinterpret_cast<const int4*>(&Bh[goB]);
            *reinterpret_cast<int4*>(&BsL[c * 8]) = *reinterpret_cast<const int4*>(&Bl[goB]);
        }
        __syncthreads();

        bf16x8 aH[4], aL[4], bH[4], bL[4];
#pragma unroll
        for (int mi = 0; mi < 4; mi++) {
            const int r = (wm + mi * 16 + rsel) * 32 + qk;
            aH[mi] = *reinterpret_cast<bf16x8*>(&AsH[r]);
            aL[mi] = *reinterpret_cast<bf16x8*>(&AsL[r]);
        }
#pragma unroll
        for (int ni = 0; ni < 4; ni++) {
            const int r = (wn + ni * 16 + rsel) * 32 + qk;
            bH[ni] = *reinterpret_cast<bf16x8*>(&BsH[r]);
            bL[ni] = *reinterpret_cast<bf16x8*>(&BsL[r]);
        }

#pragma unroll
        for (int mi = 0; mi < 4; mi++)
#pragma unroll
            for (int ni = 0; ni < 4; ni++) {
                acc[mi][ni] = __builtin_amdgcn_mfma_f32_16x16x32_bf16(aH[mi], bH[ni], acc[mi][ni], 0, 0, 0);
                acc[mi][ni] = __builtin_amdgcn_mfma_f32_16x16x32_bf16(aH[mi], bL[ni], acc[mi][ni], 0, 0, 0);
                acc[mi][ni] = __builtin_amdgcn_mfma_f32_16x16x32_bf16(aL[mi], bH[ni], acc[mi][ni], 0, 0, 0);
            }

        __syncthreads();
    }

    const int col = lane & 15;
    const int quad = lane >> 4;
#pragma unroll
    for (int mi = 0; mi < 4; mi++)
#pragma unroll
        for (int ni = 0; ni < 4; ni++) {
            const int m = m0 + wm + mi * 16 + quad * 4;
            const int n = n0 + wn + ni * 16 + col;
            float* dst = &C[(size_t)m * HH + n];
#pragma unroll
            for (int r = 0; r < 4; r++)
                dst[(size_t)r * HH] = acc[mi][ni][r];
        }
}

// ---------------------------------------------------------------------------
// LIF scan (f64 arithmetic on fp32 x_proj) + near-threshold lane flagging.
// ---------------------------------------------------------------------------
__global__ __launch_bounds__(256) void lif_scan_flag(const float* __restrict__ xp,
                                                     unsigned short* __restrict__ sp,
                                                     int* __restrict__ count,
                                                     int* __restrict__ list) {
    const int idx = blockIdx.x * 256 + threadIdx.x;
    double v = 0.0;
    bool flg = false;
#pragma unroll 4
    for (int t = 0; t < TT; t++) {
        const double x = (double)xp[(size_t)t * NLANE + idx];
        const double h = v + (x - v) * 0.5;
        const bool s = (h >= 1.0);
        flg |= (fabs(h - 1.0) < DELTA);
        v = s ? 0.0 : h;
        sp[(size_t)t * NLANE + idx] = s ? (unsigned short)0x3F80 : (unsigned short)0;
    }
    if (flg) {
        const int i = atomicAdd(count, 1);
        list[i] = idx;
    }
}

// ---------------------------------------------------------------------------
// Task-parallel exact f64 dots for flagged lanes: one WAVE per (li, t) task.
// task = li*TT + t ; 64 lanes stride K, shuffle-reduce, lane0 writes
// hraw[li*TT + t].  Grid-stride over cnt*TT tasks.
// ---------------------------------------------------------------------------
__global__ __launch_bounds__(256) void recompute_dots(const float* __restrict__ X,
                                                      const float* __restrict__ W1,
                                                      const int* __restrict__ count,
                                                      const int* __restrict__ list,
                                                      double* __restrict__ hraw) {
    const int cnt = *count;
    const int lim = (cnt < CAPL ? cnt : CAPL);
    const long ntask = (long)lim * TT;
    const int ln = threadIdx.x & 63;
    const long wid = (long)blockIdx.x * 4 + (threadIdx.x >> 6);
    const long nwaves = (long)gridDim.x * 4;

    for (long task = wid; task < ntask; task += nwaves) {
        const int li = (int)(task >> 7);
        const int t = (int)(task & (TT - 1));
        const int lane = list[li];
        const int b = lane >> 10;
        const int h = lane & (HH - 1);
        const float* xrow = X + (size_t)(t * BB + b) * HH;
        const float* wrow = W1 + (size_t)h * HH;

        double s = 0.0;
#pragma unroll 4
        for (int k = ln; k < HH; k += 64)
            s = fma((double)xrow[k], (double)wrow[k], s);
#pragma unroll
        for (int off = 32; off >= 1; off >>= 1)
            s += __shfl_down(s, off);
        if (ln == 0) hraw[task] = s;
    }
}

// ---------------------------------------------------------------------------
// Exact f64 rescan of flagged lanes from hraw; overwrite their spikes.
// One thread per flagged lane.  Serial-dot fallback for li >= CAPL keeps
// correctness independent of the capacity estimate (never triggers).
// ---------------------------------------------------------------------------
__global__ __launch_bounds__(256) void rescan_lanes(const float* __restrict__ X,
                                                    const float* __restrict__ W1,
                                                    const int* __restrict__ count,
                                                    const int* __restrict__ list,
                                                    const double* __restrict__ hraw,
                                                    unsigned short* __restrict__ sp) {
    const int li = blockIdx.x * 256 + threadIdx.x;
    const int cnt = *count;
    if (li >= cnt) return;
    const int lane = list[li];

    double v = 0.0;
    if (li < CAPL) {
        const double* hb = hraw + (size_t)li * TT;
        for (int t = 0; t < TT; t++) {
            const double h = v + (hb[t] - v) * 0.5;
            const bool s = (h >= 1.0);
            v = s ? 0.0 : h;
            sp[(size_t)t * NLANE + lane] = s ? (unsigned short)0x3F80 : (unsigned short)0;
        }
    } else {
        const int b = lane >> 10;
        const int h = lane & (HH - 1);
        const float* wrow = W1 + (size_t)h * HH;
        for (int t = 0; t < TT; t++) {
            const float* xrow = X + (size_t)(t * BB + b) * HH;
            double d = 0.0;
            for (int k = 0; k < HH; k++)
                d = fma((double)xrow[k], (double)wrow[k], d);
            const double hh = v + (d - v) * 0.5;
            const bool s = (hh >= 1.0);
            v = s ? 0.0 : hh;
            sp[(size_t)t * NLANE + lane] = s ? (unsigned short)0x3F80 : (unsigned short)0;
        }
    }
}

// ---------------------------------------------------------------------------
// GEMM2: out = S · W2^T in bf16 MFMA (validated rounds 1-2, unchanged).
// ---------------------------------------------------------------------------
__global__ __launch_bounds__(256) void gemm2_mfma(const unsigned short* __restrict__ S,
                                                  const unsigned short* __restrict__ W,
                                                  float* __restrict__ O) {
    __shared__ short As[128 * 32];
    __shared__ short Bs[128 * 32];

    const int tid = threadIdx.x;
    const int lane = tid & 63;
    const int wave = tid >> 6;
    const int m0 = blockIdx.x * 128;
    const int n0 = blockIdx.y * 128;
    const int wm = (wave >> 1) * 64;
    const int wn = (wave & 1) * 64;

    const int rsel = lane & 15;
    const int qk = (lane >> 4) * 8;

    f32x4 acc[4][4] = {};

    for (int k0 = 0; k0 < HH; k0 += 32) {
#pragma unroll
        for (int p = 0; p < 2; p++) {
            const int c = tid + p * 256;
            const int row = c >> 2;
            const int part = c & 3;
            *reinterpret_cast<int4*>(&As[c * 8]) =
                *reinterpret_cast<const int4*>(&S[(size_t)(m0 + row) * HH + k0 + part * 8]);
            *reinterpret_cast<int4*>(&Bs[c * 8]) =
                *reinterpret_cast<const int4*>(&W[(size_t)(n0 + row) * HH + k0 + part * 8]);
        }
        __syncthreads();

        bf16x8 a[4], b[4];
#pragma unroll
        for (int mi = 0; mi < 4; mi++)
            a[mi] = *reinterpret_cast<bf16x8*>(&As[(wm + mi * 16 + rsel) * 32 + qk]);
#pragma unroll
        for (int ni = 0; ni < 4; ni++)
            b[ni] = *reinterpret_cast<bf16x8*>(&Bs[(wn + ni * 16 + rsel) * 32 + qk]);

#pragma unroll
        for (int mi = 0; mi < 4; mi++)
#pragma unroll
            for (int ni = 0; ni < 4; ni++)
                acc[mi][ni] = __builtin_amdgcn_mfma_f32_16x16x32_bf16(
                    a[mi], b[ni], acc[mi][ni], 0, 0, 0);

        __syncthreads();
    }

    const int col = lane & 15;
    const int quad = lane >> 4;
#pragma unroll
    for (int mi = 0; mi < 4; mi++)
#pragma unroll
        for (int ni = 0; ni < 4; ni++) {
            const int m = m0 + wm + mi * 16 + quad * 4;
            const int n = n0 + wn + ni * 16 + col;
            float* dst = &O[(size_t)m * HH + n];
#pragma unroll
            for (int r = 0; r < 4; r++)
                dst[(size_t)r * HH] = acc[mi][ni][r];
        }
}

// ---------------------------------------------------------------------------
// Launch
// ---------------------------------------------------------------------------
extern "C" void kernel_launch(void* const* d_in, const int* in_sizes, int n_in,
                              void* d_out, int out_size, void* d_ws, size_t ws_size,
                              hipStream_t stream) {
    const float* x  = (const float*)d_in[0];
    const float* W1 = (const float*)d_in[1];
    const float* W2 = (const float*)d_in[2];
    float* out = (float*)d_out;

    char* ws = (char*)d_ws;
    const size_t szX = (size_t)MM * HH;
    const size_t szW = (size_t)HH * HH;

    unsigned short* Xhi  = (unsigned short*)ws;                       // 16.78 MB
    unsigned short* Xlo  = Xhi + szX;                                 // 16.78 MB
    unsigned short* W1hi = Xlo + szX;                                 //  2 MB
    unsigned short* W1lo = W1hi + szW;                                //  2 MB
    unsigned short* w2b  = W1lo + szW;                                //  2 MB
    int*            list = (int*)(w2b + szW);                         // 256 KB
    int*            cnt  = list + NLANE;                              // 4 B
    float*          xp   = (float*)(((uintptr_t)(cnt + 64) + 255) & ~(uintptr_t)255); // 33.5 MB
    unsigned short* sp   = Xhi;   // overlay: spikes reuse Xhi after gemm1
    double*         hraw = (double*)xp;  // overlay: xp dead after lif_scan_flag

    hipMemsetAsync(cnt, 0, sizeof(int), stream);

    split2_kernel<<<(int)(szX / 4 / 256), 256, 0, stream>>>(x, Xhi, Xlo, (int)(szX / 4));
    split2_kernel<<<(int)(szW / 4 / 256), 256, 0, stream>>>(W1, W1hi, W1lo, (int)(szW / 4));
    cast_bf16<<<(int)((szW + 255) / 256), 256, 0, stream>>>(W2, w2b, (int)szW);

    dim3 g1(MM / 128, HH / 128);
    gemm1_mfma<<<g1, 256, 0, stream>>>(Xhi, Xlo, W1hi, W1lo, xp);

    lif_scan_flag<<<NLANE / 256, 256, 0, stream>>>(xp, sp, cnt, list);

    recompute_dots<<<2048, 256, 0, stream>>>(x, W1, cnt, list, hraw);
    rescan_lanes<<<NLANE / 256, 256, 0, stream>>>(x, W1, cnt, list, hraw, sp);

    dim3 g2(MM / 128, HH / 128);
    gemm2_mfma<<<g2, 256, 0, stream>>>(sp, w2b, out);
}

// Round 4
// 258.866 us; speedup vs baseline: 3.5098x; 1.0195x over previous
//
#include <hip/hip_runtime.h>
#include <hip/hip_bf16.h>
#include <stdint.h>

// Problem constants (T=128, B=64, H=1024)
#define TT 128
#define BB 64
#define HH 1024
#define MM (TT * BB)          // 8192 rows of the two GEMMs
#define NLANE (BB * HH)       // 65536 scan lanes
#define DELTA 3.0e-4          // flag band (worst-case dropped-term bound ~1.2e-4)
#define CAPL 32768            // hraw capacity in lanes (overlay on xp region)

typedef __attribute__((ext_vector_type(8))) short bf16x8;
typedef __attribute__((ext_vector_type(4))) float f32x4;

// async global->LDS, 16 B per lane; LDS dest = wave-uniform base + lane*16
#define GLOAD16(g, l)                                                        \
    __builtin_amdgcn_global_load_lds(                                        \
        (const __attribute__((address_space(1))) unsigned int*)(g),          \
        (__attribute__((address_space(3))) unsigned int*)(l), 16, 0, 0)

static __device__ __forceinline__ unsigned short bf16_bits(float f) {
    __hip_bfloat16 b = __float2bfloat16(f);
    return *reinterpret_cast<unsigned short*>(&b);
}

// ---------------------------------------------------------------------------
// Split fp32 -> bf16 hi + bf16 lo (hi = bf16(x), lo = bf16(x - hi)).
// ---------------------------------------------------------------------------
__global__ __launch_bounds__(256) void split2_kernel(const float* __restrict__ src,
                                                     unsigned short* __restrict__ hi,
                                                     unsigned short* __restrict__ lo,
                                                     int n4) {
    const int i = blockIdx.x * 256 + threadIdx.x;
    if (i >= n4) return;
    float4 x = reinterpret_cast<const float4*>(src)[i];
    float v[4] = {x.x, x.y, x.z, x.w};
    unsigned short hb[4], lb[4];
#pragma unroll
    for (int c = 0; c < 4; c++) {
        hb[c] = bf16_bits(v[c]);
        __hip_bfloat16 hh = *reinterpret_cast<__hip_bfloat16*>(&hb[c]);
        lb[c] = bf16_bits(v[c] - __bfloat162float(hh));
    }
    reinterpret_cast<ushort4*>(hi)[i] = make_ushort4(hb[0], hb[1], hb[2], hb[3]);
    reinterpret_cast<ushort4*>(lo)[i] = make_ushort4(lb[0], lb[1], lb[2], lb[3]);
}

// ---------------------------------------------------------------------------
// Cast W2 fp32 -> bf16 (validated: contributes absmax ~4e-3 << 2.3e-2).
// ---------------------------------------------------------------------------
__global__ __launch_bounds__(256) void cast_bf16(const float* __restrict__ src,
                                                 unsigned short* __restrict__ dst,
                                                 int n) {
    const int i = blockIdx.x * 256 + threadIdx.x;
    if (i < n) dst[i] = bf16_bits(src[i]);
}

// ---------------------------------------------------------------------------
// GEMM1 via 3-pass split-bf16 MFMA: C = XhiWhi + XhiWlo + XloWhi (fp32 accum).
// 128x128 tile, BK=32, 4 waves 2x2.  Staging now via global_load_lds(16B):
// chunk c = tid + p*256 is lane-linear per wave, LDS base wave-uniform.
// ---------------------------------------------------------------------------
__global__ __launch_bounds__(256) void gemm1_mfma(const unsigned short* __restrict__ Ah,
                                                  const unsigned short* __restrict__ Al,
                                                  const unsigned short* __restrict__ Bh,
                                                  const unsigned short* __restrict__ Bl,
                                                  float* __restrict__ C) {
    __shared__ short AsH[128 * 32];
    __shared__ short AsL[128 * 32];
    __shared__ short BsH[128 * 32];
    __shared__ short BsL[128 * 32];

    const int tid = threadIdx.x;
    const int lane = tid & 63;
    const int wave = tid >> 6;
    const int m0 = blockIdx.x * 128;
    const int n0 = blockIdx.y * 128;
    const int wm = (wave >> 1) * 64;
    const int wn = (wave & 1) * 64;

    const int rsel = lane & 15;
    const int qk = (lane >> 4) * 8;

    f32x4 acc[4][4] = {};

    for (int k0 = 0; k0 < HH; k0 += 32) {
#pragma unroll
        for (int p = 0; p < 2; p++) {
            const int c = tid + p * 256;          // this lane's chunk
            const int cb = wave * 64 + p * 256;   // wave-uniform base chunk
            const int row = c >> 2;
            const int part = c & 3;
            const size_t goA = (size_t)(m0 + row) * HH + k0 + part * 8;
            const size_t goB = (size_t)(n0 + row) * HH + k0 + part * 8;
            GLOAD16(&Ah[goA], &AsH[cb * 8]);
            GLOAD16(&Al[goA], &AsL[cb * 8]);
            GLOAD16(&Bh[goB], &BsH[cb * 8]);
            GLOAD16(&Bl[goB], &BsL[cb * 8]);
        }
        __syncthreads();

        bf16x8 aH[4], aL[4], bH[4], bL[4];
#pragma unroll
        for (int mi = 0; mi < 4; mi++) {
            const int r = (wm + mi * 16 + rsel) * 32 + qk;
            aH[mi] = *reinterpret_cast<bf16x8*>(&AsH[r]);
            aL[mi] = *reinterpret_cast<bf16x8*>(&AsL[r]);
        }
#pragma unroll
        for (int ni = 0; ni < 4; ni++) {
            const int r = (wn + ni * 16 + rsel) * 32 + qk;
            bH[ni] = *reinterpret_cast<bf16x8*>(&BsH[r]);
            bL[ni] = *reinterpret_cast<bf16x8*>(&BsL[r]);
        }

#pragma unroll
        for (int mi = 0; mi < 4; mi++)
#pragma unroll
            for (int ni = 0; ni < 4; ni++) {
                acc[mi][ni] = __builtin_amdgcn_mfma_f32_16x16x32_bf16(aH[mi], bH[ni], acc[mi][ni], 0, 0, 0);
                acc[mi][ni] = __builtin_amdgcn_mfma_f32_16x16x32_bf16(aH[mi], bL[ni], acc[mi][ni], 0, 0, 0);
                acc[mi][ni] = __builtin_amdgcn_mfma_f32_16x16x32_bf16(aL[mi], bH[ni], acc[mi][ni], 0, 0, 0);
            }

        __syncthreads();
    }

    const int col = lane & 15;
    const int quad = lane >> 4;
#pragma unroll
    for (int mi = 0; mi < 4; mi++)
#pragma unroll
        for (int ni = 0; ni < 4; ni++) {
            const int m = m0 + wm + mi * 16 + quad * 4;
            const int n = n0 + wn + ni * 16 + col;
            float* dst = &C[(size_t)m * HH + n];
#pragma unroll
            for (int r = 0; r < 4; r++)
                dst[(size_t)r * HH] = acc[mi][ni][r];
        }
}

// ---------------------------------------------------------------------------
// LIF scan (f64 arithmetic on fp32 x_proj) + near-threshold lane flagging.
// ---------------------------------------------------------------------------
__global__ __launch_bounds__(256) void lif_scan_flag(const float* __restrict__ xp,
                                                     unsigned short* __restrict__ sp,
                                                     int* __restrict__ count,
                                                     int* __restrict__ list) {
    const int idx = blockIdx.x * 256 + threadIdx.x;
    double v = 0.0;
    bool flg = false;
#pragma unroll 4
    for (int t = 0; t < TT; t++) {
        const double x = (double)xp[(size_t)t * NLANE + idx];
        const double h = v + (x - v) * 0.5;
        const bool s = (h >= 1.0);
        flg |= (fabs(h - 1.0) < DELTA);
        v = s ? 0.0 : h;
        sp[(size_t)t * NLANE + idx] = s ? (unsigned short)0x3F80 : (unsigned short)0;
    }
    if (flg) {
        const int i = atomicAdd(count, 1);
        list[i] = idx;
    }
}

// ---------------------------------------------------------------------------
// Task-parallel exact f64 dots for flagged lanes: one WAVE per (li, t) task.
// float4 loads (1 KB/inst coalesced), 4 partial f64 sums for MLP.
// ---------------------------------------------------------------------------
__global__ __launch_bounds__(256) void recompute_dots(const float* __restrict__ X,
                                                      const float* __restrict__ W1,
                                                      const int* __restrict__ count,
                                                      const int* __restrict__ list,
                                                      double* __restrict__ hraw) {
    const int cnt = *count;
    const int lim = (cnt < CAPL ? cnt : CAPL);
    const long ntask = (long)lim * TT;
    const int ln = threadIdx.x & 63;
    const long wid = (long)blockIdx.x * 4 + (threadIdx.x >> 6);
    const long nwaves = (long)gridDim.x * 4;

    for (long task = wid; task < ntask; task += nwaves) {
        const int li = (int)(task >> 7);
        const int t = (int)(task & (TT - 1));
        const int lane = list[li];
        const int b = lane >> 10;
        const int h = lane & (HH - 1);
        const float4* x4 = reinterpret_cast<const float4*>(X + (size_t)(t * BB + b) * HH);
        const float4* w4 = reinterpret_cast<const float4*>(W1 + (size_t)h * HH);

        double s0 = 0.0, s1 = 0.0, s2 = 0.0, s3 = 0.0;
#pragma unroll
        for (int i = 0; i < 4; i++) {
            const float4 xa = x4[ln + i * 64];
            const float4 wa = w4[ln + i * 64];
            s0 = fma((double)xa.x, (double)wa.x, s0);
            s1 = fma((double)xa.y, (double)wa.y, s1);
            s2 = fma((double)xa.z, (double)wa.z, s2);
            s3 = fma((double)xa.w, (double)wa.w, s3);
        }
        double s = (s0 + s1) + (s2 + s3);
#pragma unroll
        for (int off = 32; off >= 1; off >>= 1)
            s += __shfl_down(s, off);
        if (ln == 0) hraw[task] = s;
    }
}

// ---------------------------------------------------------------------------
// Exact f64 rescan of flagged lanes from hraw; overwrite their spikes.
// Serial-dot fallback for li >= CAPL keeps correctness capacity-independent.
// ---------------------------------------------------------------------------
__global__ __launch_bounds__(256) void rescan_lanes(const float* __restrict__ X,
                                                    const float* __restrict__ W1,
                                                    const int* __restrict__ count,
                                                    const int* __restrict__ list,
                                                    const double* __restrict__ hraw,
                                                    unsigned short* __restrict__ sp) {
    const int li = blockIdx.x * 256 + threadIdx.x;
    const int cnt = *count;
    if (li >= cnt) return;
    const int lane = list[li];

    double v = 0.0;
    if (li < CAPL) {
        const double* hb = hraw + (size_t)li * TT;
        for (int t = 0; t < TT; t++) {
            const double h = v + (hb[t] - v) * 0.5;
            const bool s = (h >= 1.0);
            v = s ? 0.0 : h;
            sp[(size_t)t * NLANE + lane] = s ? (unsigned short)0x3F80 : (unsigned short)0;
        }
    } else {
        const int b = lane >> 10;
        const int h = lane & (HH - 1);
        const float* wrow = W1 + (size_t)h * HH;
        for (int t = 0; t < TT; t++) {
            const float* xrow = X + (size_t)(t * BB + b) * HH;
            double d = 0.0;
            for (int k = 0; k < HH; k++)
                d = fma((double)xrow[k], (double)wrow[k], d);
            const double hh = v + (d - v) * 0.5;
            const bool s = (hh >= 1.0);
            v = s ? 0.0 : hh;
            sp[(size_t)t * NLANE + lane] = s ? (unsigned short)0x3F80 : (unsigned short)0;
        }
    }
}

// ---------------------------------------------------------------------------
// GEMM2: out = S · W2^T in bf16 MFMA; staging via global_load_lds(16B).
// ---------------------------------------------------------------------------
__global__ __launch_bounds__(256) void gemm2_mfma(const unsigned short* __restrict__ S,
                                                  const unsigned short* __restrict__ W,
                                                  float* __restrict__ O) {
    __shared__ short As[128 * 32];
    __shared__ short Bs[128 * 32];

    const int tid = threadIdx.x;
    const int lane = tid & 63;
    const int wave = tid >> 6;
    const int m0 = blockIdx.x * 128;
    const int n0 = blockIdx.y * 128;
    const int wm = (wave >> 1) * 64;
    const int wn = (wave & 1) * 64;

    const int rsel = lane & 15;
    const int qk = (lane >> 4) * 8;

    f32x4 acc[4][4] = {};

    for (int k0 = 0; k0 < HH; k0 += 32) {
#pragma unroll
        for (int p = 0; p < 2; p++) {
            const int c = tid + p * 256;
            const int cb = wave * 64 + p * 256;
            const int row = c >> 2;
            const int part = c & 3;
            GLOAD16(&S[(size_t)(m0 + row) * HH + k0 + part * 8], &As[cb * 8]);
            GLOAD16(&W[(size_t)(n0 + row) * HH + k0 + part * 8], &Bs[cb * 8]);
        }
        __syncthreads();

        bf16x8 a[4], b[4];
#pragma unroll
        for (int mi = 0; mi < 4; mi++)
            a[mi] = *reinterpret_cast<bf16x8*>(&As[(wm + mi * 16 + rsel) * 32 + qk]);
#pragma unroll
        for (int ni = 0; ni < 4; ni++)
            b[ni] = *reinterpret_cast<bf16x8*>(&Bs[(wn + ni * 16 + rsel) * 32 + qk]);

#pragma unroll
        for (int mi = 0; mi < 4; mi++)
#pragma unroll
            for (int ni = 0; ni < 4; ni++)
                acc[mi][ni] = __builtin_amdgcn_mfma_f32_16x16x32_bf16(
                    a[mi], b[ni], acc[mi][ni], 0, 0, 0);

        __syncthreads();
    }

    const int col = lane & 15;
    const int quad = lane >> 4;
#pragma unroll
    for (int mi = 0; mi < 4; mi++)
#pragma unroll
        for (int ni = 0; ni < 4; ni++) {
            const int m = m0 + wm + mi * 16 + quad * 4;
            const int n = n0 + wn + ni * 16 + col;
            float* dst = &O[(size_t)m * HH + n];
#pragma unroll
            for (int r = 0; r < 4; r++)
                dst[(size_t)r * HH] = acc[mi][ni][r];
        }
}

// ---------------------------------------------------------------------------
// Launch
// ---------------------------------------------------------------------------
extern "C" void kernel_launch(void* const* d_in, const int* in_sizes, int n_in,
                              void* d_out, int out_size, void* d_ws, size_t ws_size,
                              hipStream_t stream) {
    const float* x  = (const float*)d_in[0];
    const float* W1 = (const float*)d_in[1];
    const float* W2 = (const float*)d_in[2];
    float* out = (float*)d_out;

    char* ws = (char*)d_ws;
    const size_t szX = (size_t)MM * HH;
    const size_t szW = (size_t)HH * HH;

    unsigned short* Xhi  = (unsigned short*)ws;                       // 16.78 MB
    unsigned short* Xlo  = Xhi + szX;                                 // 16.78 MB
    unsigned short* W1hi = Xlo + szX;                                 //  2 MB
    unsigned short* W1lo = W1hi + szW;                                //  2 MB
    unsigned short* w2b  = W1lo + szW;                                //  2 MB
    int*            list = (int*)(w2b + szW);                         // 256 KB
    int*            cnt  = list + NLANE;                              // 4 B
    float*          xp   = (float*)(((uintptr_t)(cnt + 64) + 255) & ~(uintptr_t)255); // 33.5 MB
    unsigned short* sp   = Xhi;   // overlay: spikes reuse Xhi after gemm1
    double*         hraw = (double*)xp;  // overlay: xp dead after lif_scan_flag

    hipMemsetAsync(cnt, 0, sizeof(int), stream);

    split2_kernel<<<(int)(szX / 4 / 256), 256, 0, stream>>>(x, Xhi, Xlo, (int)(szX / 4));
    split2_kernel<<<(int)(szW / 4 / 256), 256, 0, stream>>>(W1, W1hi, W1lo, (int)(szW / 4));
    cast_bf16<<<(int)((szW + 255) / 256), 256, 0, stream>>>(W2, w2b, (int)szW);

    dim3 g1(MM / 128, HH / 128);
    gemm1_mfma<<<g1, 256, 0, stream>>>(Xhi, Xlo, W1hi, W1lo, xp);

    lif_scan_flag<<<NLANE / 256, 256, 0, stream>>>(xp, sp, cnt, list);

    recompute_dots<<<2048, 256, 0, stream>>>(x, W1, cnt, list, hraw);
    rescan_lanes<<<NLANE / 256, 256, 0, stream>>>(x, W1, cnt, list, hraw, sp);

    dim3 g2(MM / 128, HH / 128);
    gemm2_mfma<<<g2, 256, 0, stream>>>(sp, w2b, out);
}

// Round 5
// 258.512 us; speedup vs baseline: 3.5146x; 1.0014x over previous
//
#include <hip/hip_runtime.h>
#include <hip/hip_bf16.h>
#include <stdint.h>

// Problem constants (T=128, B=64, H=1024)
#define TT 128
#define BB 64
#define HH 1024
#define MM (TT * BB)          // 8192 rows of the two GEMMs
#define NLANE (BB * HH)       // 65536 scan lanes
#define DELTA 3.0e-5          // flag band; fp16-split error budget ~3e-6 (10x margin)
#define CAPL 32768            // hraw capacity in lanes (overlay on xp region)
#define LO_SCALE 4096.0f      // lo stored scaled by 2^12 (own accumulator, no flush)
#define F16_ONE 0x3C00        // _Float16 1.0

typedef __attribute__((ext_vector_type(8))) _Float16 f16x8;
typedef __attribute__((ext_vector_type(4))) float f32x4;

// async global->LDS, 16 B per lane; LDS dest = wave-uniform base + lane*16
#define GLOAD16(g, l)                                                        \
    __builtin_amdgcn_global_load_lds(                                        \
        (const __attribute__((address_space(1))) unsigned int*)(g),          \
        (__attribute__((address_space(3))) unsigned int*)(l), 16, 0, 0)

static __device__ __forceinline__ unsigned short f16_bits(float f) {
    _Float16 h = (_Float16)f;
    return *reinterpret_cast<unsigned short*>(&h);
}

// ---------------------------------------------------------------------------
// Split fp32 -> f16 hi + f16 lo*4096 (hi = f16(x), lo = f16((x-hi)*4096)).
// x - (float)hi is exact (<=13 significant bits); scaled lo keeps 11 bits.
// ---------------------------------------------------------------------------
__global__ __launch_bounds__(256) void split2_kernel(const float* __restrict__ src,
                                                     unsigned short* __restrict__ hi,
                                                     unsigned short* __restrict__ lo,
                                                     int n4) {
    const int i = blockIdx.x * 256 + threadIdx.x;
    if (i >= n4) return;
    float4 x = reinterpret_cast<const float4*>(src)[i];
    float v[4] = {x.x, x.y, x.z, x.w};
    unsigned short hb[4], lb[4];
#pragma unroll
    for (int c = 0; c < 4; c++) {
        _Float16 hh = (_Float16)v[c];
        hb[c] = *reinterpret_cast<unsigned short*>(&hh);
        lb[c] = f16_bits((v[c] - (float)hh) * LO_SCALE);
    }
    reinterpret_cast<ushort4*>(hi)[i] = make_ushort4(hb[0], hb[1], hb[2], hb[3]);
    reinterpret_cast<ushort4*>(lo)[i] = make_ushort4(lb[0], lb[1], lb[2], lb[3]);
}

// ---------------------------------------------------------------------------
// Cast W2 fp32 -> f16 (spikes exact {0,1}; f16 W2 rounding ~5e-4 << 2.3e-2).
// ---------------------------------------------------------------------------
__global__ __launch_bounds__(256) void cast_f16(const float* __restrict__ src,
                                                unsigned short* __restrict__ dst,
                                                int n) {
    const int i = blockIdx.x * 256 + threadIdx.x;
    if (i < n) dst[i] = f16_bits(src[i]);
}

// ---------------------------------------------------------------------------
// GEMM1 via 3-pass split-f16 MFMA: acc1 = XhiWhi ; acc2 = Xhi*Wlo' + Xlo'*Whi
// (lo' = lo*4096) ; C = acc1 + acc2/4096.  128x128 tile, BK=32, 4 waves 2x2.
// LDS XOR-swizzled: chunk (row,part) stored at slot part^((row>>1)&3) ->
// fragment reads hit 32 banks at 2 lanes/bank (free, m136).
// ---------------------------------------------------------------------------
__global__ __launch_bounds__(256) void gemm1_mfma(const unsigned short* __restrict__ Ah,
                                                  const unsigned short* __restrict__ Al,
                                                  const unsigned short* __restrict__ Bh,
                                                  const unsigned short* __restrict__ Bl,
                                                  float* __restrict__ C) {
    __shared__ short AsH[128 * 32];
    __shared__ short AsL[128 * 32];
    __shared__ short BsH[128 * 32];
    __shared__ short BsL[128 * 32];

    const int tid = threadIdx.x;
    const int lane = tid & 63;
    const int wave = tid >> 6;
    const int m0 = blockIdx.x * 128;
    const int n0 = blockIdx.y * 128;
    const int wm = (wave >> 1) * 64;
    const int wn = (wave & 1) * 64;

    const int rsel = lane & 15;
    const int part = lane >> 4;   // which 8-elem k-section this lane reads

    // loop-invariant swizzled fragment addresses (short index)
    int adrA[4], adrB[4];
#pragma unroll
    for (int i = 0; i < 4; i++) {
        const int ra = wm + i * 16 + rsel;
        const int rb = wn + i * 16 + rsel;
        adrA[i] = ra * 32 + (part ^ ((ra >> 1) & 3)) * 8;
        adrB[i] = rb * 32 + (part ^ ((rb >> 1) & 3)) * 8;
    }

    f32x4 acc1[4][4] = {};
    f32x4 acc2[4][4] = {};

    for (int k0 = 0; k0 < HH; k0 += 32) {
#pragma unroll
        for (int p = 0; p < 2; p++) {
            const int c = tid + p * 256;          // this lane's LDS chunk slot
            const int cb = wave * 64 + p * 256;   // wave-uniform base chunk
            const int row = c >> 2;
            const int pslot = c & 3;
            const int pdata = pslot ^ ((row >> 1) & 3);   // global part staged here
            const size_t goA = (size_t)(m0 + row) * HH + k0 + pdata * 8;
            const size_t goB = (size_t)(n0 + row) * HH + k0 + pdata * 8;
            GLOAD16(&Ah[goA], &AsH[cb * 8]);
            GLOAD16(&Al[goA], &AsL[cb * 8]);
            GLOAD16(&Bh[goB], &BsH[cb * 8]);
            GLOAD16(&Bl[goB], &BsL[cb * 8]);
        }
        __syncthreads();

        f16x8 aH[4], aL[4], bH[4], bL[4];
#pragma unroll
        for (int mi = 0; mi < 4; mi++) {
            aH[mi] = *reinterpret_cast<f16x8*>(&AsH[adrA[mi]]);
            aL[mi] = *reinterpret_cast<f16x8*>(&AsL[adrA[mi]]);
        }
#pragma unroll
        for (int ni = 0; ni < 4; ni++) {
            bH[ni] = *reinterpret_cast<f16x8*>(&BsH[adrB[ni]]);
            bL[ni] = *reinterpret_cast<f16x8*>(&BsL[adrB[ni]]);
        }

#pragma unroll
        for (int mi = 0; mi < 4; mi++)
#pragma unroll
            for (int ni = 0; ni < 4; ni++) {
                acc1[mi][ni] = __builtin_amdgcn_mfma_f32_16x16x32_f16(aH[mi], bH[ni], acc1[mi][ni], 0, 0, 0);
                acc2[mi][ni] = __builtin_amdgcn_mfma_f32_16x16x32_f16(aH[mi], bL[ni], acc2[mi][ni], 0, 0, 0);
                acc2[mi][ni] = __builtin_amdgcn_mfma_f32_16x16x32_f16(aL[mi], bH[ni], acc2[mi][ni], 0, 0, 0);
            }

        __syncthreads();
    }

    const int col = lane & 15;
    const int quad = lane >> 4;
    const float inv = 1.0f / LO_SCALE;
#pragma unroll
    for (int mi = 0; mi < 4; mi++)
#pragma unroll
        for (int ni = 0; ni < 4; ni++) {
            const int m = m0 + wm + mi * 16 + quad * 4;
            const int n = n0 + wn + ni * 16 + col;
            float* dst = &C[(size_t)m * HH + n];
#pragma unroll
            for (int r = 0; r < 4; r++)
                dst[(size_t)r * HH] = fmaf(acc2[mi][ni][r], inv, acc1[mi][ni][r]);
        }
}

// ---------------------------------------------------------------------------
// LIF scan (f64 arithmetic on fp32 x_proj) + near-threshold lane flagging.
// ---------------------------------------------------------------------------
__global__ __launch_bounds__(256) void lif_scan_flag(const float* __restrict__ xp,
                                                     unsigned short* __restrict__ sp,
                                                     int* __restrict__ count,
                                                     int* __restrict__ list) {
    const int idx = blockIdx.x * 256 + threadIdx.x;
    double v = 0.0;
    bool flg = false;
#pragma unroll 4
    for (int t = 0; t < TT; t++) {
        const double x = (double)xp[(size_t)t * NLANE + idx];
        const double h = v + (x - v) * 0.5;
        const bool s = (h >= 1.0);
        flg |= (fabs(h - 1.0) < DELTA);
        v = s ? 0.0 : h;
        sp[(size_t)t * NLANE + idx] = s ? (unsigned short)F16_ONE : (unsigned short)0;
    }
    if (flg) {
        const int i = atomicAdd(count, 1);
        list[i] = idx;
    }
}

// ---------------------------------------------------------------------------
// Task-parallel exact f64 dots for flagged lanes: one WAVE per (li, t) task.
// ---------------------------------------------------------------------------
__global__ __launch_bounds__(256) void recompute_dots(const float* __restrict__ X,
                                                      const float* __restrict__ W1,
                                                      const int* __restrict__ count,
                                                      const int* __restrict__ list,
                                                      double* __restrict__ hraw) {
    const int cnt = *count;
    const int lim = (cnt < CAPL ? cnt : CAPL);
    const long ntask = (long)lim * TT;
    const int ln = threadIdx.x & 63;
    const long wid = (long)blockIdx.x * 4 + (threadIdx.x >> 6);
    const long nwaves = (long)gridDim.x * 4;

    for (long task = wid; task < ntask; task += nwaves) {
        const int li = (int)(task >> 7);
        const int t = (int)(task & (TT - 1));
        const int lane = list[li];
        const int b = lane >> 10;
        const int h = lane & (HH - 1);
        const float4* x4 = reinterpret_cast<const float4*>(X + (size_t)(t * BB + b) * HH);
        const float4* w4 = reinterpret_cast<const float4*>(W1 + (size_t)h * HH);

        double s0 = 0.0, s1 = 0.0, s2 = 0.0, s3 = 0.0;
#pragma unroll
        for (int i = 0; i < 4; i++) {
            const float4 xa = x4[ln + i * 64];
            const float4 wa = w4[ln + i * 64];
            s0 = fma((double)xa.x, (double)wa.x, s0);
            s1 = fma((double)xa.y, (double)wa.y, s1);
            s2 = fma((double)xa.z, (double)wa.z, s2);
            s3 = fma((double)xa.w, (double)wa.w, s3);
        }
        double s = (s0 + s1) + (s2 + s3);
#pragma unroll
        for (int off = 32; off >= 1; off >>= 1)
            s += __shfl_down(s, off);
        if (ln == 0) hraw[task] = s;
    }
}

// ---------------------------------------------------------------------------
// Exact f64 rescan of flagged lanes from hraw; overwrite their spikes.
// Serial-dot fallback for li >= CAPL keeps correctness capacity-independent.
// ---------------------------------------------------------------------------
__global__ __launch_bounds__(256) void rescan_lanes(const float* __restrict__ X,
                                                    const float* __restrict__ W1,
                                                    const int* __restrict__ count,
                                                    const int* __restrict__ list,
                                                    const double* __restrict__ hraw,
                                                    unsigned short* __restrict__ sp) {
    const int li = blockIdx.x * 256 + threadIdx.x;
    const int cnt = *count;
    if (li >= cnt) return;
    const int lane = list[li];

    double v = 0.0;
    if (li < CAPL) {
        const double* hb = hraw + (size_t)li * TT;
        for (int t = 0; t < TT; t++) {
            const double h = v + (hb[t] - v) * 0.5;
            const bool s = (h >= 1.0);
            v = s ? 0.0 : h;
            sp[(size_t)t * NLANE + lane] = s ? (unsigned short)F16_ONE : (unsigned short)0;
        }
    } else {
        const int b = lane >> 10;
        const int h = lane & (HH - 1);
        const float* wrow = W1 + (size_t)h * HH;
        for (int t = 0; t < TT; t++) {
            const float* xrow = X + (size_t)(t * BB + b) * HH;
            double d = 0.0;
            for (int k = 0; k < HH; k++)
                d = fma((double)xrow[k], (double)wrow[k], d);
            const double hh = v + (d - v) * 0.5;
            const bool s = (hh >= 1.0);
            v = s ? 0.0 : hh;
            sp[(size_t)t * NLANE + lane] = s ? (unsigned short)F16_ONE : (unsigned short)0;
        }
    }
}

// ---------------------------------------------------------------------------
// GEMM2: out = S · W2^T in f16 MFMA, same swizzled-LDS structure.
// ---------------------------------------------------------------------------
__global__ __launch_bounds__(256) void gemm2_mfma(const unsigned short* __restrict__ S,
                                                  const unsigned short* __restrict__ W,
                                                  float* __restrict__ O) {
    __shared__ short As[128 * 32];
    __shared__ short Bs[128 * 32];

    const int tid = threadIdx.x;
    const int lane = tid & 63;
    const int wave = tid >> 6;
    const int m0 = blockIdx.x * 128;
    const int n0 = blockIdx.y * 128;
    const int wm = (wave >> 1) * 64;
    const int wn = (wave & 1) * 64;

    const int rsel = lane & 15;
    const int part = lane >> 4;

    int adrA[4], adrB[4];
#pragma unroll
    for (int i = 0; i < 4; i++) {
        const int ra = wm + i * 16 + rsel;
        const int rb = wn + i * 16 + rsel;
        adrA[i] = ra * 32 + (part ^ ((ra >> 1) & 3)) * 8;
        adrB[i] = rb * 32 + (part ^ ((rb >> 1) & 3)) * 8;
    }

    f32x4 acc[4][4] = {};

    for (int k0 = 0; k0 < HH; k0 += 32) {
#pragma unroll
        for (int p = 0; p < 2; p++) {
            const int c = tid + p * 256;
            const int cb = wave * 64 + p * 256;
            const int row = c >> 2;
            const int pslot = c & 3;
            const int pdata = pslot ^ ((row >> 1) & 3);
            GLOAD16(&S[(size_t)(m0 + row) * HH + k0 + pdata * 8], &As[cb * 8]);
            GLOAD16(&W[(size_t)(n0 + row) * HH + k0 + pdata * 8], &Bs[cb * 8]);
        }
        __syncthreads();

        f16x8 a[4], b[4];
#pragma unroll
        for (int mi = 0; mi < 4; mi++)
            a[mi] = *reinterpret_cast<f16x8*>(&As[adrA[mi]]);
#pragma unroll
        for (int ni = 0; ni < 4; ni++)
            b[ni] = *reinterpret_cast<f16x8*>(&Bs[adrB[ni]]);

#pragma unroll
        for (int mi = 0; mi < 4; mi++)
#pragma unroll
            for (int ni = 0; ni < 4; ni++)
                acc[mi][ni] = __builtin_amdgcn_mfma_f32_16x16x32_f16(
                    a[mi], b[ni], acc[mi][ni], 0, 0, 0);

        __syncthreads();
    }

    const int col = lane & 15;
    const int quad = lane >> 4;
#pragma unroll
    for (int mi = 0; mi < 4; mi++)
#pragma unroll
        for (int ni = 0; ni < 4; ni++) {
            const int m = m0 + wm + mi * 16 + quad * 4;
            const int n = n0 + wn + ni * 16 + col;
            float* dst = &O[(size_t)m * HH + n];
#pragma unroll
            for (int r = 0; r < 4; r++)
                dst[(size_t)r * HH] = acc[mi][ni][r];
        }
}

// ---------------------------------------------------------------------------
// Launch
// ---------------------------------------------------------------------------
extern "C" void kernel_launch(void* const* d_in, const int* in_sizes, int n_in,
                              void* d_out, int out_size, void* d_ws, size_t ws_size,
                              hipStream_t stream) {
    const float* x  = (const float*)d_in[0];
    const float* W1 = (const float*)d_in[1];
    const float* W2 = (const float*)d_in[2];
    float* out = (float*)d_out;

    char* ws = (char*)d_ws;
    const size_t szX = (size_t)MM * HH;
    const size_t szW = (size_t)HH * HH;

    unsigned short* Xhi  = (unsigned short*)ws;                       // 16.78 MB
    unsigned short* Xlo  = Xhi + szX;                                 // 16.78 MB
    unsigned short* W1hi = Xlo + szX;                                 //  2 MB
    unsigned short* W1lo = W1hi + szW;                                //  2 MB
    unsigned short* w2h  = W1lo + szW;                                //  2 MB
    int*            list = (int*)(w2h + szW);                         // 256 KB
    int*            cnt  = list + NLANE;                              // 4 B
    float*          xp   = (float*)(((uintptr_t)(cnt + 64) + 255) & ~(uintptr_t)255); // 33.5 MB
    unsigned short* sp   = Xhi;   // overlay: spikes reuse Xhi after gemm1
    double*         hraw = (double*)xp;  // overlay: xp dead after lif_scan_flag

    hipMemsetAsync(cnt, 0, sizeof(int), stream);

    split2_kernel<<<(int)(szX / 4 / 256), 256, 0, stream>>>(x, Xhi, Xlo, (int)(szX / 4));
    split2_kernel<<<(int)(szW / 4 / 256), 256, 0, stream>>>(W1, W1hi, W1lo, (int)(szW / 4));
    cast_f16<<<(int)((szW + 255) / 256), 256, 0, stream>>>(W2, w2h, (int)szW);

    dim3 g1(MM / 128, HH / 128);
    gemm1_mfma<<<g1, 256, 0, stream>>>(Xhi, Xlo, W1hi, W1lo, xp);

    lif_scan_flag<<<NLANE / 256, 256, 0, stream>>>(xp, sp, cnt, list);

    recompute_dots<<<2048, 256, 0, stream>>>(x, W1, cnt, list, hraw);
    rescan_lanes<<<NLANE / 256, 256, 0, stream>>>(x, W1, cnt, list, hraw, sp);

    dim3 g2(MM / 128, HH / 128);
    gemm2_mfma<<<g2, 256, 0, stream>>>(sp, w2h, out);
}

// Round 6
// 231.227 us; speedup vs baseline: 3.9293x; 1.1180x over previous
//
#include <hip/hip_runtime.h>
#include <hip/hip_bf16.h>
#include <stdint.h>

// Problem constants (T=128, B=64, H=1024)
#define TT 128
#define BB 64
#define HH 1024
#define MM (TT * BB)          // 8192 rows of the two GEMMs
#define NLANE (BB * HH)       // 65536 scan lanes
#define DELTA 3.0e-5          // flag band; fp16-split error budget ~1e-6 (30x margin)
#define LO_SCALE 4096.0f      // lo stored scaled by 2^12 (avoids f16 subnormal loss)
#define INV_LO (1.0f / 4096.0f)
#define F16_ONE 0x3C00        // _Float16 1.0

typedef __attribute__((ext_vector_type(8))) _Float16 f16x8;
typedef __attribute__((ext_vector_type(4))) float f32x4;

// async global->LDS, 16 B per lane; LDS dest = wave-uniform base + lane*16
#define GLOAD16(g, l)                                                        \
    __builtin_amdgcn_global_load_lds(                                        \
        (const __attribute__((address_space(1))) unsigned int*)(g),          \
        (__attribute__((address_space(3))) unsigned int*)(l), 16, 0, 0)

static __device__ __forceinline__ unsigned short f16_bits(float f) {
    _Float16 h = (_Float16)f;
    return *reinterpret_cast<unsigned short*>(&h);
}

// ---------------------------------------------------------------------------
// Fused prep (one dispatch instead of 4):
//   blocks [0,8192)      : split X  -> Xhi, Xlo*4096   (2097152 float4)
//   blocks [8192,9216)   : split W1 -> W1hi, W1lo*4096 (262144 float4)
//   blocks [9216,10240)  : cast  W2 -> f16             (262144 float4)
//   block 0 thread 0     : cnt = 0 (replaces hipMemsetAsync)
// ---------------------------------------------------------------------------
__global__ __launch_bounds__(256) void prep_fused(const float* __restrict__ x,
                                                  const float* __restrict__ W1,
                                                  const float* __restrict__ W2,
                                                  unsigned short* __restrict__ Xhi,
                                                  unsigned short* __restrict__ Xlo,
                                                  unsigned short* __restrict__ W1hi,
                                                  unsigned short* __restrict__ W1lo,
                                                  unsigned short* __restrict__ w2h,
                                                  int* __restrict__ cnt) {
    const int bid = blockIdx.x;
    if (bid == 0 && threadIdx.x == 0) *cnt = 0;

    const float* src;
    unsigned short *hi, *lo;
    int i;
    bool split;
    if (bid < 8192) {
        i = bid * 256 + threadIdx.x;
        src = x; hi = Xhi; lo = Xlo; split = true;
    } else if (bid < 9216) {
        i = (bid - 8192) * 256 + threadIdx.x;
        src = W1; hi = W1hi; lo = W1lo; split = true;
    } else {
        i = (bid - 9216) * 256 + threadIdx.x;
        src = W2; hi = w2h; lo = nullptr; split = false;
    }

    float4 v4 = reinterpret_cast<const float4*>(src)[i];
    float v[4] = {v4.x, v4.y, v4.z, v4.w};
    unsigned short hb[4], lb[4];
#pragma unroll
    for (int c = 0; c < 4; c++) {
        _Float16 hh = (_Float16)v[c];
        hb[c] = *reinterpret_cast<unsigned short*>(&hh);
        if (split) lb[c] = f16_bits((v[c] - (float)hh) * LO_SCALE);
    }
    reinterpret_cast<ushort4*>(hi)[i] = make_ushort4(hb[0], hb[1], hb[2], hb[3]);
    if (split)
        reinterpret_cast<ushort4*>(lo)[i] = make_ushort4(lb[0], lb[1], lb[2], lb[3]);
}

// ---------------------------------------------------------------------------
// GEMM1 via split-f16 MFMA, SINGLE accumulator:
//   per K-iter: acc += aH·bH ; tmp = aH·bL' + aL'·bH (2 MFMAs from zero);
//   acc += tmp * 2^-12 (4 v_fmac).  (lo' = lo*4096.)
// Keeps acc at 64 AGPRs (round-5's dual-acc 128 caused the occupancy cliff).
// 128x128 tile, BK=32, 4 waves 2x2; LDS XOR-swizzled (conflicts=0, round 5).
// ---------------------------------------------------------------------------
__global__ __launch_bounds__(256) void gemm1_mfma(const unsigned short* __restrict__ Ah,
                                                  const unsigned short* __restrict__ Al,
                                                  const unsigned short* __restrict__ Bh,
                                                  const unsigned short* __restrict__ Bl,
                                                  float* __restrict__ C) {
    __shared__ short AsH[128 * 32];
    __shared__ short AsL[128 * 32];
    __shared__ short BsH[128 * 32];
    __shared__ short BsL[128 * 32];

    const int tid = threadIdx.x;
    const int lane = tid & 63;
    const int wave = tid >> 6;
    const int m0 = blockIdx.x * 128;
    const int n0 = blockIdx.y * 128;
    const int wm = (wave >> 1) * 64;
    const int wn = (wave & 1) * 64;

    const int rsel = lane & 15;
    const int part = lane >> 4;

    int adrA[4], adrB[4];
#pragma unroll
    for (int i = 0; i < 4; i++) {
        const int ra = wm + i * 16 + rsel;
        const int rb = wn + i * 16 + rsel;
        adrA[i] = ra * 32 + (part ^ ((ra >> 1) & 3)) * 8;
        adrB[i] = rb * 32 + (part ^ ((rb >> 1) & 3)) * 8;
    }

    f32x4 acc[4][4] = {};
    const f32x4 zero = {0.0f, 0.0f, 0.0f, 0.0f};

    for (int k0 = 0; k0 < HH; k0 += 32) {
#pragma unroll
        for (int p = 0; p < 2; p++) {
            const int c = tid + p * 256;
            const int cb = wave * 64 + p * 256;
            const int row = c >> 2;
            const int pslot = c & 3;
            const int pdata = pslot ^ ((row >> 1) & 3);
            const size_t goA = (size_t)(m0 + row) * HH + k0 + pdata * 8;
            const size_t goB = (size_t)(n0 + row) * HH + k0 + pdata * 8;
            GLOAD16(&Ah[goA], &AsH[cb * 8]);
            GLOAD16(&Al[goA], &AsL[cb * 8]);
            GLOAD16(&Bh[goB], &BsH[cb * 8]);
            GLOAD16(&Bl[goB], &BsL[cb * 8]);
        }
        __syncthreads();

        f16x8 aH[4], aL[4], bH[4], bL[4];
#pragma unroll
        for (int mi = 0; mi < 4; mi++) {
            aH[mi] = *reinterpret_cast<f16x8*>(&AsH[adrA[mi]]);
            aL[mi] = *reinterpret_cast<f16x8*>(&AsL[adrA[mi]]);
        }
#pragma unroll
        for (int ni = 0; ni < 4; ni++) {
            bH[ni] = *reinterpret_cast<f16x8*>(&BsH[adrB[ni]]);
            bL[ni] = *reinterpret_cast<f16x8*>(&BsL[adrB[ni]]);
        }

        // main-term MFMAs (16 independent)
#pragma unroll
        for (int mi = 0; mi < 4; mi++)
#pragma unroll
            for (int ni = 0; ni < 4; ni++)
                acc[mi][ni] = __builtin_amdgcn_mfma_f32_16x16x32_f16(
                    aH[mi], bH[ni], acc[mi][ni], 0, 0, 0);

        // correction terms folded into the same accumulator (scaled 2^-12)
#pragma unroll
        for (int mi = 0; mi < 4; mi++)
#pragma unroll
            for (int ni = 0; ni < 4; ni++) {
                f32x4 t = __builtin_amdgcn_mfma_f32_16x16x32_f16(aH[mi], bL[ni], zero, 0, 0, 0);
                t = __builtin_amdgcn_mfma_f32_16x16x32_f16(aL[mi], bH[ni], t, 0, 0, 0);
#pragma unroll
                for (int r = 0; r < 4; r++)
                    acc[mi][ni][r] = fmaf(t[r], INV_LO, acc[mi][ni][r]);
            }

        __syncthreads();
    }

    const int col = lane & 15;
    const int quad = lane >> 4;
#pragma unroll
    for (int mi = 0; mi < 4; mi++)
#pragma unroll
        for (int ni = 0; ni < 4; ni++) {
            const int m = m0 + wm + mi * 16 + quad * 4;
            const int n = n0 + wn + ni * 16 + col;
            float* dst = &C[(size_t)m * HH + n];
#pragma unroll
            for (int r = 0; r < 4; r++)
                dst[(size_t)r * HH] = acc[mi][ni][r];
        }
}

// ---------------------------------------------------------------------------
// LIF scan (f64 arithmetic on fp32 x_proj) + near-threshold lane flagging.
// ---------------------------------------------------------------------------
__global__ __launch_bounds__(256) void lif_scan_flag(const float* __restrict__ xp,
                                                     unsigned short* __restrict__ sp,
                                                     int* __restrict__ count,
                                                     int* __restrict__ list) {
    const int idx = blockIdx.x * 256 + threadIdx.x;
    double v = 0.0;
    bool flg = false;
#pragma unroll 4
    for (int t = 0; t < TT; t++) {
        const double x = (double)xp[(size_t)t * NLANE + idx];
        const double h = v + (x - v) * 0.5;
        const bool s = (h >= 1.0);
        flg |= (fabs(h - 1.0) < DELTA);
        v = s ? 0.0 : h;
        sp[(size_t)t * NLANE + idx] = s ? (unsigned short)F16_ONE : (unsigned short)0;
    }
    if (flg) {
        const int i = atomicAdd(count, 1);
        list[i] = idx;
    }
}

// ---------------------------------------------------------------------------
// Fused exact-recompute for flagged lanes (one dispatch, no hraw buffer):
// block <- flagged lane (grid-stride).  4 waves x 32 t-dots each in f64
// (float4 coalesced loads, shuffle-reduce) -> LDS hbuf[128]; then thread 0
// runs the exact f64 scan and overwrites the lane's spikes.  Correct for any
// cnt (grid-stride), no capacity fallback needed.
// ---------------------------------------------------------------------------
__global__ __launch_bounds__(256) void recompute_fused(const float* __restrict__ X,
                                                       const float* __restrict__ W1,
                                                       const int* __restrict__ count,
                                                       const int* __restrict__ list,
                                                       unsigned short* __restrict__ sp) {
    __shared__ double hbuf[TT];
    const int cnt = *count;
    const int wv = threadIdx.x >> 6;
    const int ln = threadIdx.x & 63;

    for (int li = blockIdx.x; li < cnt; li += gridDim.x) {
        const int lane = list[li];
        const int b = lane >> 10;
        const int h = lane & (HH - 1);
        const float4* w4 = reinterpret_cast<const float4*>(W1 + (size_t)h * HH);

        for (int t = wv; t < TT; t += 4) {
            const float4* x4 = reinterpret_cast<const float4*>(X + (size_t)(t * BB + b) * HH);
            double s0 = 0.0, s1 = 0.0, s2 = 0.0, s3 = 0.0;
#pragma unroll
            for (int i = 0; i < 4; i++) {
                const float4 xa = x4[ln + i * 64];
                const float4 wa = w4[ln + i * 64];
                s0 = fma((double)xa.x, (double)wa.x, s0);
                s1 = fma((double)xa.y, (double)wa.y, s1);
                s2 = fma((double)xa.z, (double)wa.z, s2);
                s3 = fma((double)xa.w, (double)wa.w, s3);
            }
            double s = (s0 + s1) + (s2 + s3);
#pragma unroll
            for (int off = 32; off >= 1; off >>= 1)
                s += __shfl_down(s, off);
            if (ln == 0) hbuf[t] = s;
        }
        __syncthreads();

        if (threadIdx.x == 0) {
            double v = 0.0;
            for (int t = 0; t < TT; t++) {
                const double hh = v + (hbuf[t] - v) * 0.5;
                const bool s = (hh >= 1.0);
                v = s ? 0.0 : hh;
                sp[(size_t)t * NLANE + lane] = s ? (unsigned short)F16_ONE : (unsigned short)0;
            }
        }
        __syncthreads();
    }
}

// ---------------------------------------------------------------------------
// GEMM2: out = S · W2^T in f16 MFMA, swizzled LDS (validated round 5).
// ---------------------------------------------------------------------------
__global__ __launch_bounds__(256) void gemm2_mfma(const unsigned short* __restrict__ S,
                                                  const unsigned short* __restrict__ W,
                                                  float* __restrict__ O) {
    __shared__ short As[128 * 32];
    __shared__ short Bs[128 * 32];

    const int tid = threadIdx.x;
    const int lane = tid & 63;
    const int wave = tid >> 6;
    const int m0 = blockIdx.x * 128;
    const int n0 = blockIdx.y * 128;
    const int wm = (wave >> 1) * 64;
    const int wn = (wave & 1) * 64;

    const int rsel = lane & 15;
    const int part = lane >> 4;

    int adrA[4], adrB[4];
#pragma unroll
    for (int i = 0; i < 4; i++) {
        const int ra = wm + i * 16 + rsel;
        const int rb = wn + i * 16 + rsel;
        adrA[i] = ra * 32 + (part ^ ((ra >> 1) & 3)) * 8;
        adrB[i] = rb * 32 + (part ^ ((rb >> 1) & 3)) * 8;
    }

    f32x4 acc[4][4] = {};

    for (int k0 = 0; k0 < HH; k0 += 32) {
#pragma unroll
        for (int p = 0; p < 2; p++) {
            const int c = tid + p * 256;
            const int cb = wave * 64 + p * 256;
            const int row = c >> 2;
            const int pslot = c & 3;
            const int pdata = pslot ^ ((row >> 1) & 3);
            GLOAD16(&S[(size_t)(m0 + row) * HH + k0 + pdata * 8], &As[cb * 8]);
            GLOAD16(&W[(size_t)(n0 + row) * HH + k0 + pdata * 8], &Bs[cb * 8]);
        }
        __syncthreads();

        f16x8 a[4], b[4];
#pragma unroll
        for (int mi = 0; mi < 4; mi++)
            a[mi] = *reinterpret_cast<f16x8*>(&As[adrA[mi]]);
#pragma unroll
        for (int ni = 0; ni < 4; ni++)
            b[ni] = *reinterpret_cast<f16x8*>(&Bs[adrB[ni]]);

#pragma unroll
        for (int mi = 0; mi < 4; mi++)
#pragma unroll
            for (int ni = 0; ni < 4; ni++)
                acc[mi][ni] = __builtin_amdgcn_mfma_f32_16x16x32_f16(
                    a[mi], b[ni], acc[mi][ni], 0, 0, 0);

        __syncthreads();
    }

    const int col = lane & 15;
    const int quad = lane >> 4;
#pragma unroll
    for (int mi = 0; mi < 4; mi++)
#pragma unroll
        for (int ni = 0; ni < 4; ni++) {
            const int m = m0 + wm + mi * 16 + quad * 4;
            const int n = n0 + wn + ni * 16 + col;
            float* dst = &O[(size_t)m * HH + n];
#pragma unroll
            for (int r = 0; r < 4; r++)
                dst[(size_t)r * HH] = acc[mi][ni][r];
        }
}

// ---------------------------------------------------------------------------
// Launch (5 dispatches)
// ---------------------------------------------------------------------------
extern "C" void kernel_launch(void* const* d_in, const int* in_sizes, int n_in,
                              void* d_out, int out_size, void* d_ws, size_t ws_size,
                              hipStream_t stream) {
    const float* x  = (const float*)d_in[0];
    const float* W1 = (const float*)d_in[1];
    const float* W2 = (const float*)d_in[2];
    float* out = (float*)d_out;

    char* ws = (char*)d_ws;
    const size_t szX = (size_t)MM * HH;
    const size_t szW = (size_t)HH * HH;

    unsigned short* Xhi  = (unsigned short*)ws;                       // 16.78 MB
    unsigned short* Xlo  = Xhi + szX;                                 // 16.78 MB
    unsigned short* W1hi = Xlo + szX;                                 //  2 MB
    unsigned short* W1lo = W1hi + szW;                                //  2 MB
    unsigned short* w2h  = W1lo + szW;                                //  2 MB
    int*            list = (int*)(w2h + szW);                         // 256 KB
    int*            cnt  = list + NLANE;                              // 4 B
    float*          xp   = (float*)(((uintptr_t)(cnt + 64) + 255) & ~(uintptr_t)255); // 33.5 MB
    unsigned short* sp   = Xhi;   // overlay: spikes reuse Xhi after gemm1

    prep_fused<<<10240, 256, 0, stream>>>(x, W1, W2, Xhi, Xlo, W1hi, W1lo, w2h, cnt);

    dim3 g1(MM / 128, HH / 128);
    gemm1_mfma<<<g1, 256, 0, stream>>>(Xhi, Xlo, W1hi, W1lo, xp);

    lif_scan_flag<<<NLANE / 256, 256, 0, stream>>>(xp, sp, cnt, list);

    recompute_fused<<<1024, 256, 0, stream>>>(x, W1, cnt, list, sp);

    dim3 g2(MM / 128, HH / 128);
    gemm2_mfma<<<g2, 256, 0, stream>>>(sp, w2h, out);
}